// Round 4
// baseline (258.527 us; speedup 1.0000x reference)
//
#include <hip/hip_runtime.h>
#include <hip/hip_bf16.h>
#include <math.h>

#define DEVI static __device__ __forceinline__

using f32x4  = __attribute__((ext_vector_type(4))) float;
using f32x16 = __attribute__((ext_vector_type(16))) float;
using s16x8  = __attribute__((ext_vector_type(8))) short;
using bf16x8 = __attribute__((ext_vector_type(8))) __bf16;
using i32x4  = __attribute__((ext_vector_type(4))) int;
using u32x2  = __attribute__((ext_vector_type(2))) unsigned int;
using u32x4  = __attribute__((ext_vector_type(4))) unsigned int;

constexpr int N   = 8192;
constexpr int KIN = 512;
constexpr int F   = 256;

DEVI unsigned f2bf(float f) {
  unsigned u = __builtin_bit_cast(unsigned, f);
  return ((u + 0x7FFFu + ((u >> 16) & 1u)) >> 16) & 0xFFFFu;
}

DEVI unsigned cvtpk(float lo, float hi) {
  unsigned r;
  asm("v_cvt_pk_bf16_f32 %0, %1, %2" : "=v"(r) : "v"(lo), "v"(hi));
  return r;
}

DEVI f32x16 mfma32(s16x8 a, s16x8 b, f32x16 c) {
  return __builtin_amdgcn_mfma_f32_32x32x16_bf16(
      __builtin_bit_cast(bf16x8, a), __builtin_bit_cast(bf16x8, b), c, 0, 0, 0);
}

DEVI void gload16(const void* g, void* lds_uniform) {
  __builtin_amdgcn_global_load_lds(
      (const __attribute__((address_space(1))) unsigned*)g,
      (__attribute__((address_space(3))) unsigned*)lds_uniform, 16, 0, 0);
}

// ---------------- cast input f32 -> bf16 (row-major [8192][512]) ----------------
__global__ __launch_bounds__(256) void k_cast(const float* __restrict__ src,
                                              unsigned short* __restrict__ dst,
                                              int n8) {
  int t = blockIdx.x * 256 + threadIdx.x;
  if (t >= n8) return;
  const f32x4* p = (const f32x4*)(src + (size_t)t * 8);
  f32x4 v0 = p[0], v1 = p[1];
  s16x8 o;
  o[0] = (short)f2bf(v0[0]); o[1] = (short)f2bf(v0[1]);
  o[2] = (short)f2bf(v0[2]); o[3] = (short)f2bf(v0[3]);
  o[4] = (short)f2bf(v1[0]); o[5] = (short)f2bf(v1[1]);
  o[6] = (short)f2bf(v1[2]); o[7] = (short)f2bf(v1[3]);
  *(s16x8*)(dst + (size_t)t * 8) = o;
}

// ---------------- W [512][256] f32 -> Wt [256][512] bf16 (transposed) -----------
__global__ __launch_bounds__(256) void k_prep_w(const float* __restrict__ W,
                                                unsigned short* __restrict__ Wt) {
  int t = blockIdx.x * 256 + threadIdx.x;   // 16384 threads
  int c = t >> 6, k0 = (t & 63) * 8;
  s16x8 o;
#pragma unroll
  for (int i = 0; i < 8; ++i) o[i] = (short)f2bf(W[(size_t)(k0 + i) * F + c]);
  *(s16x8*)(Wt + (size_t)c * KIN + k0) = o;
}

// ---------------- h = Xbf @ Wt^T : writes Ht[256][8192] bf16 + E/E5/F/F5 --------
__global__ __launch_bounds__(512) void k_gemm1(const unsigned short* __restrict__ inpb,
                                               const unsigned short* __restrict__ Wt,
                                               const float* __restrict__ a_vec,
                                               unsigned short* __restrict__ Ht,
                                               float* __restrict__ E, float* __restrict__ E5,
                                               float* __restrict__ Fv, float* __restrict__ F5v) {
  __shared__ __align__(16) char lds[4096 + 32768 + 2048];
  char* ldsA = lds;                 // [32 rows][128 B]  (XOR-swizzled)
  char* ldsW = lds + 4096;          // [256 cols][128 B] (XOR-swizzled)
  float* red = (float*)(lds + 36864); // [2][32][8]
  int tid = threadIdx.x, w = tid >> 6, l = tid & 63;
  int r0 = blockIdx.x * 32;
  f32x16 acc;
#pragma unroll
  for (int i = 0; i < 16; ++i) acc[i] = 0.f;

  int lrow8 = l >> 3;
  int koffB = ((l & 7) ^ lrow8) * 8;   // pre-swizzled source k-offset (elements)
  int ra = l & 31, kb = (l >> 5) * 8;
  int colw = w * 32 + ra;

  for (int it = 0; it < 8; ++it) {
    int k0 = it * 64;
    __syncthreads();
    if (w < 4) {
      int row = 8 * w + lrow8;
      gload16(inpb + (size_t)(r0 + row) * KIN + k0 + koffB, ldsA + w * 1024);
    }
#pragma unroll
    for (int qi = 0; qi < 4; ++qi) {
      int q = 4 * w + qi;
      int c = 8 * q + lrow8;
      gload16(Wt + (size_t)c * KIN + k0 + koffB, ldsW + q * 1024);
    }
    __syncthreads();
    s16x8 av[4], bv[4];
#pragma unroll
    for (int kf = 0; kf < 4; ++kf) {
      int kk2 = (kf * 16 + kb) * 2;
      av[kf] = *(const s16x8*)(ldsA + ra * 128 + (kk2 ^ ((ra & 7) << 4)));
      bv[kf] = *(const s16x8*)(ldsW + colw * 128 + (kk2 ^ ((colw & 7) << 4)));
    }
#pragma unroll
    for (int kf = 0; kf < 4; ++kf) acc = mfma32(av[kf], bv[kf], acc);
  }

  float a1 = a_vec[colw], a2 = a_vec[256 + colw];
  int rquad = (l >> 5) * 4;
#pragma unroll
  for (int g = 0; g < 4; ++g) {
    int rowb = g * 8 + rquad;
    unsigned h0 = f2bf(acc[g * 4 + 0]), h1 = f2bf(acc[g * 4 + 1]);
    unsigned h2 = f2bf(acc[g * 4 + 2]), h3 = f2bf(acc[g * 4 + 3]);
    u32x2 pk;
    pk[0] = h0 | (h1 << 16);
    pk[1] = h2 | (h3 << 16);
    *(u32x2*)(Ht + (size_t)colw * N + r0 + rowb) = pk;
  }
#pragma unroll
  for (int g = 0; g < 16; ++g) {
    float vs = acc[g] * a1;
    float vn = acc[g] * a2;
#pragma unroll
    for (int m = 1; m <= 16; m <<= 1) {
      vs += __shfl_xor(vs, m, 64);
      vn += __shfl_xor(vn, m, 64);
    }
    if ((l & 31) == 0) {
      int row = (g & 3) + 8 * (g >> 2) + rquad;
      red[row * 8 + w] = vs;
      red[256 + row * 8 + w] = vn;
    }
  }
  __syncthreads();
  if (tid < 32) {
    float s = 0.f, n2 = 0.f;
#pragma unroll
    for (int i = 0; i < 8; ++i) { s += red[tid * 8 + i]; n2 += red[256 + tid * 8 + i]; }
    E[r0 + tid]   = expf(s);
    E5[r0 + tid]  = expf(0.2f * s);
    Fv[r0 + tid]  = expf(n2);
    F5v[r0 + tid] = expf(0.2f * n2);
  }
}

// ---------------- fused masked-softmax @ h: P-ring in LDS, H direct from L2 -----
// 256 blocks x 32 rows, 512 threads (8 waves; wave w owns feature cols w*32..+31).
// j swept in 64 tiles of 128, per-block phase rotation de-syncs the adj stream.
// LDS: only a ring of 4 P-tiles [32 rows][128 j] bf16 (XOR-swizzled) = 32 KB ->
// 2 blocks/CU. Per iter: produce P(t+2) cooperatively (inputs reg-prefetched 1
// iter ahead), ONE s_barrier, consume P(t) (A-frags from LDS, B-frags loaded
// straight from L2-resident Ht, 16B/lane coalesced). Ring-4 + produce-2-ahead
// + 1 barrier/iter is race-free: slot s reused 4 barriers after its consumers'
// lgkmcnt(0)-drained reads. No vmcnt waits anywhere - loads float freely.
__global__ __launch_bounds__(512, 4) void k_phase2(const int* __restrict__ adj,
                                                   const unsigned short* __restrict__ Ht,
                                                   const float* __restrict__ E,
                                                   const float* __restrict__ E5,
                                                   const float* __restrict__ Fv,
                                                   const float* __restrict__ F5v,
                                                   float* __restrict__ out) {
  __shared__ __align__(16) char lds[32768 + 128];
  char* ldsP = lds;                        // 4 x [32][128] bf16, swizzled
  float* ldsS = (float*)(lds + 32768);     // [32] 1/rowsum

  const int tid = threadIdx.x, w = tid >> 6, l = tid & 63;
  const int r0 = blockIdx.x * 32;
  const int start = (blockIdx.x * 13) & 63;   // j-phase rotation

  // producer role: thread covers row r, cols cch*8..cch*8+7 of each 128-j tile
  const int r = tid >> 4;
  const int cch = tid & 15;
  const float Er = E[r0 + r], E5r = E5[r0 + r];
  float s_part = 0.f;
  const int pw_byte = r * 256 + ((cch * 16) ^ ((r & 7) << 4) ^ (((r >> 3) & 1) << 7));
  const int* adjR = adj + (size_t)(r0 + r) * N;

  // consumer role: wave w, feature col = colw; A-frag row = l&31, k-half = l>>5
  const int colw = w * 32 + (l & 31);
  const unsigned short* HtBase = Ht + (size_t)colw * N + (l >> 5) * 8;
  const int abase = (l & 31) * 256 + (((l >> 5) * 16) ^ ((l & 7) << 4) ^ (((l >> 3) & 1) << 7));

  f32x16 acc;
#pragma unroll
  for (int i = 0; i < 16; ++i) acc[i] = 0.f;

  // ---- prologue: produce P(0),P(1) into slots 0,1 (rowsum NOT accumulated:
  // tiles start,start+1 are re-produced as P(64),P(65) in-loop where the loop's
  // 64 produces cover every tile exactly once) ----
#pragma unroll
  for (int q = 0; q < 2; ++q) {
    const int tile = (start + q) & 63;
    const i32x4* ap = (const i32x4*)(adjR + tile * 128 + cch * 8);
    i32x4 a0 = ap[0], a1 = ap[1];
    const f32x4* fp = (const f32x4*)(Fv + tile * 128 + cch * 8);
    f32x4 f0 = fp[0], f1 = fp[1];
    const f32x4* gp = (const f32x4*)(F5v + tile * 128 + cch * 8);
    f32x4 g0 = gp[0], g1 = gp[1];
    float p0 = (a0[0] != 0) ? fmaxf(Er * f0[0], E5r * g0[0]) : 0.f;
    float p1 = (a0[1] != 0) ? fmaxf(Er * f0[1], E5r * g0[1]) : 0.f;
    float p2 = (a0[2] != 0) ? fmaxf(Er * f0[2], E5r * g0[2]) : 0.f;
    float p3 = (a0[3] != 0) ? fmaxf(Er * f0[3], E5r * g0[3]) : 0.f;
    float p4 = (a1[0] != 0) ? fmaxf(Er * f1[0], E5r * g1[0]) : 0.f;
    float p5 = (a1[1] != 0) ? fmaxf(Er * f1[1], E5r * g1[1]) : 0.f;
    float p6 = (a1[2] != 0) ? fmaxf(Er * f1[2], E5r * g1[2]) : 0.f;
    float p7 = (a1[3] != 0) ? fmaxf(Er * f1[3], E5r * g1[3]) : 0.f;
    u32x4 pk;
    pk[0] = cvtpk(p0, p1); pk[1] = cvtpk(p2, p3);
    pk[2] = cvtpk(p4, p5); pk[3] = cvtpk(p6, p7);
    *(u32x4*)(ldsP + q * 8192 + pw_byte) = pk;
  }
  // load reg-set 1 with inputs for tile start+2 (consumed at body t=0)
  i32x4 ad00 = {}, ad01 = {}, ad10, ad11;
  f32x4 f00 = {}, f01 = {}, g00 = {}, g01 = {}, f10, f11, g10, g11;
  {
    const int tile = (start + 2) & 63;
    const i32x4* ap = (const i32x4*)(adjR + tile * 128 + cch * 8);
    ad10 = ap[0]; ad11 = ap[1];
    const f32x4* fp = (const f32x4*)(Fv + tile * 128 + cch * 8);
    f10 = fp[0]; f11 = fp[1];
    const f32x4* gp = (const f32x4*)(F5v + tile * 128 + cch * 8);
    g10 = gp[0]; g11 = gp[1];
  }

#define P2_BODY(U, ADI0,ADI1,FI0,FI1,GI0,GI1, ADC0,ADC1,FC0,FC1,GC0,GC1)       \
  {                                                                            \
    const int t     = ito * 4 + (U);                                           \
    const int tileC = (start + t) & 63;                                        \
    const int tileL = (start + t + 3) & 63;                                    \
    /* B-frags for consume tile: straight from L2-resident Ht, issued early */ \
    const s16x8* hb = (const s16x8*)(HtBase + tileC * 128);                    \
    s16x8 b0 = hb[0], b1 = hb[2], b2 = hb[4], b3 = hb[6];                      \
    s16x8 b4 = hb[8], b5 = hb[10], b6 = hb[12], b7 = hb[14];                   \
    /* reg-prefetch inputs for tile t+3 into the issue set */                  \
    {                                                                          \
      const i32x4* ap = (const i32x4*)(adjR + tileL * 128 + cch * 8);          \
      ADI0 = ap[0]; ADI1 = ap[1];                                              \
      const f32x4* fp = (const f32x4*)(Fv + tileL * 128 + cch * 8);            \
      FI0 = fp[0]; FI1 = fp[1];                                                \
      const f32x4* gp = (const f32x4*)(F5v + tileL * 128 + cch * 8);           \
      GI0 = gp[0]; GI1 = gp[1];                                                \
    }                                                                          \
    /* produce P(t+2) into slot (t+2)&3 from the consume set */                \
    {                                                                          \
      float p0 = (ADC0[0] != 0) ? fmaxf(Er * FC0[0], E5r * GC0[0]) : 0.f;      \
      float p1 = (ADC0[1] != 0) ? fmaxf(Er * FC0[1], E5r * GC0[1]) : 0.f;      \
      float p2 = (ADC0[2] != 0) ? fmaxf(Er * FC0[2], E5r * GC0[2]) : 0.f;      \
      float p3 = (ADC0[3] != 0) ? fmaxf(Er * FC0[3], E5r * GC0[3]) : 0.f;      \
      float p4 = (ADC1[0] != 0) ? fmaxf(Er * FC1[0], E5r * GC1[0]) : 0.f;      \
      float p5 = (ADC1[1] != 0) ? fmaxf(Er * FC1[1], E5r * GC1[1]) : 0.f;      \
      float p6 = (ADC1[2] != 0) ? fmaxf(Er * FC1[2], E5r * GC1[2]) : 0.f;      \
      float p7 = (ADC1[3] != 0) ? fmaxf(Er * FC1[3], E5r * GC1[3]) : 0.f;      \
      s_part += ((p0 + p1) + (p2 + p3)) + ((p4 + p5) + (p6 + p7));             \
      u32x4 pk;                                                                \
      pk[0] = cvtpk(p0, p1); pk[1] = cvtpk(p2, p3);                            \
      pk[2] = cvtpk(p4, p5); pk[3] = cvtpk(p6, p7);                            \
      *(u32x4*)(ldsP + (((U) + 2) & 3) * 8192 + pw_byte) = pk;                 \
    }                                                                          \
    asm volatile("s_waitcnt lgkmcnt(0)" ::: "memory");                         \
    __builtin_amdgcn_s_barrier();                                              \
    /* consume P(t) from slot U&3 */                                           \
    {                                                                          \
      char* Pr = ldsP + ((U) & 3) * 8192;                                      \
      s16x8 a0 = *(const s16x8*)(Pr + (abase ^ (0 << 5)));                     \
      s16x8 a1 = *(const s16x8*)(Pr + (abase ^ (1 << 5)));                     \
      s16x8 a2 = *(const s16x8*)(Pr + (abase ^ (2 << 5)));                     \
      s16x8 a3 = *(const s16x8*)(Pr + (abase ^ (3 << 5)));                     \
      asm volatile("s_waitcnt lgkmcnt(0)" ::: "memory");                       \
      __builtin_amdgcn_sched_barrier(0);                                       \
      acc = mfma32(a0, b0, acc);                                               \
      acc = mfma32(a1, b1, acc);                                               \
      acc = mfma32(a2, b2, acc);                                               \
      acc = mfma32(a3, b3, acc);                                               \
      s16x8 a4 = *(const s16x8*)(Pr + (abase ^ (4 << 5)));                     \
      s16x8 a5 = *(const s16x8*)(Pr + (abase ^ (5 << 5)));                     \
      s16x8 a6 = *(const s16x8*)(Pr + (abase ^ (6 << 5)));                     \
      s16x8 a7 = *(const s16x8*)(Pr + (abase ^ (7 << 5)));                     \
      asm volatile("s_waitcnt lgkmcnt(0)" ::: "memory");                       \
      __builtin_amdgcn_sched_barrier(0);                                       \
      acc = mfma32(a4, b4, acc);                                               \
      acc = mfma32(a5, b5, acc);                                               \
      acc = mfma32(a6, b6, acc);                                               \
      acc = mfma32(a7, b7, acc);                                               \
    }                                                                          \
  }

  for (int ito = 0; ito < 16; ++ito) {
    P2_BODY(0, ad00,ad01,f00,f01,g00,g01, ad10,ad11,f10,f11,g10,g11)
    P2_BODY(1, ad10,ad11,f10,f11,g10,g11, ad00,ad01,f00,f01,g00,g01)
    P2_BODY(2, ad00,ad01,f00,f01,g00,g01, ad10,ad11,f10,f11,g10,g11)
    P2_BODY(3, ad10,ad11,f10,f11,g10,g11, ad00,ad01,f00,f01,g00,g01)
  }
#undef P2_BODY

  // ---- epilogue: rowsum -> 1/s (16 producer-threads per row), normalize, ELU ---
  __syncthreads();
  float s = s_part;
#pragma unroll
  for (int m = 1; m <= 8; m <<= 1) s += __shfl_xor(s, m, 64);
  if ((tid & 15) == 0) ldsS[r] = 1.f / s;
  __syncthreads();
#pragma unroll
  for (int g = 0; g < 16; ++g) {
    int row = (g & 3) + 8 * (g >> 2) + 4 * (l >> 5);
    float v = acc[g] * ldsS[row];
    out[(size_t)(r0 + row) * F + colw] = v > 0.f ? v : expm1f(v);
  }
}

extern "C" void kernel_launch(void* const* d_in, const int* in_sizes, int n_in,
                              void* d_out, int out_size, void* d_ws, size_t ws_size,
                              hipStream_t stream) {
  const float* input = (const float*)d_in[0];
  const int*   adj   = (const int*)d_in[1];
  const float* W     = (const float*)d_in[2];
  const float* a     = (const float*)d_in[3];
  float* out = (float*)d_out;
  char* ws = (char*)d_ws;

  unsigned short* inpb = (unsigned short*)(ws);              // 8,388,608 B
  unsigned short* Wt   = (unsigned short*)(ws + 8388608);    //   262,144 B
  unsigned short* Ht   = (unsigned short*)(ws + 8650752);    // 4,194,304 B
  float* E    = (float*)(ws + 12845056);                     //    32,768 B
  float* E5   = (float*)(ws + 12877824);
  float* Fv   = (float*)(ws + 12910592);
  float* F5   = (float*)(ws + 12943360);

  hipLaunchKernelGGL(k_cast,   dim3(2048), dim3(256), 0, stream, input, inpb, 524288);
  hipLaunchKernelGGL(k_prep_w, dim3(64),   dim3(256), 0, stream, W, Wt);
  hipLaunchKernelGGL(k_gemm1,  dim3(256),  dim3(512), 0, stream, inpb, Wt, a, Ht, E, E5, Fv, F5);
  hipLaunchKernelGGL(k_phase2, dim3(256),  dim3(512), 0, stream, adj, Ht, E, E5, Fv, F5, out);
}